// Round 21
// baseline (1053.751 us; speedup 1.0000x reference)
//
#include <hip/hip_runtime.h>

// RNN: h_t = tanh(x[b,t]*W_ih + b_ih + b_hh + h_{t-1} @ W_hh^T), out = h_T @ W_out^T + b_out
// B=256 T=2048 H=256 P=24, fp32 in/out. One WG/batch (256 WGs = 256 CUs), 512 thr, 8 waves.
//
// Round-27 (3rd resubmit; R18/R20 GPUAcquisitionTimeout, R19 container fail):
// PIPE-SPLIT HYBRID. R17 (844us): MFMA pipe busy 54%, VALU 32% --
// each pipe idles while the other's structure runs. m114: MFMA-wave +
// VALU-wave on one SIMD co-issue fully. And no pure-MFMA arrangement beats
// ~620cyc/SIMD/step (M-replication waste is invariant). So split the rows
// across pipes, one wave of each type per SIMD:
//  - Waves 0-3 (MFMA path, rows 0-127): exact R17 structure -- wf[2][8],
//    broadcast A reads, zero-C split-K chains, setprio around the cluster,
//    early rb0 tail. ~310 cyc matrix pipe per SIMD-step.
//  - Waves 4-7 (vector path, rows 128-255): exact R12-fp16 structure --
//    fdot2 j-outer chains, 8-slot select-free DPP butterfly
//    (m={0,2,7,5,8,10,15,13}, 0x128/0x141/0x4E/0xB1), 2-dup same-addr
//    writes. ~320 cyc VALU per SIMD-step.
// One h store in the padded HSTRH=24 layout serves both: vector reads
// unchanged (chunk c at 24c halfs, 2x hoct); MFMA broadcast read address
// adapts: padded(k)=24*(k>>4)+(k&15), k=32kb+8kg+j -> half-offset
// 48kb + 24*(kg>>1) + 8*(kg&1) (16B-aligned; 4 distinct bank-quads,
// conflict-free). Writes: MFMA writer lanes cover rows 0-127 (no dup);
// vector lanes cover 128-255 (2-dup same-addr).
// absmax: MFMA rows ~3.9e-3 class, dot2 rows ~7.8e-3 class -> ~7.8e-3.
// Locked-in: fp16 h storage; lgkm-only barrier; x block-prefetch; fp32
// tanh (exp2/rcp); fp32 head on tid<24; launch_bounds(512,2).

#define BB 256
#define TT 2048
#define HH 256
#define PP 24
#define HSTRH 24   // h chunk stride in HALFS: 16 data + 8 pad (48B)

typedef _Float16 half_t;
typedef _Float16 h2  __attribute__((ext_vector_type(2)));
typedef _Float16 h8v __attribute__((ext_vector_type(8)));
typedef float    f4v __attribute__((ext_vector_type(4)));

struct alignas(16) hoct { h2 v[4]; };   // 8 halfs = one ds_read_b128

__device__ __forceinline__ int hidx16(int k) { return (k >> 4) * HSTRH + (k & 15); }

template<int CTRL>
__device__ __forceinline__ float dppadd(float dst, float src) {
    return dst + __int_as_float(__builtin_amdgcn_update_dpp(
        0, __float_as_int(src), CTRL, 0xf, 0xf, true));
}

__device__ __forceinline__ float fdot2f(h2 a, h2 b, float c) {
#if __has_builtin(__builtin_amdgcn_fdot2)
    return __builtin_amdgcn_fdot2(a, b, c, false);
#else
    return fmaf((float)a.x, (float)b.x, fmaf((float)a.y, (float)b.y, c));
#endif
}

__device__ __forceinline__ f4v mfma16(h8v a, h8v b, f4v c) {
    return __builtin_amdgcn_mfma_f32_16x16x32_f16(a, b, c, 0, 0, 0);
}

// LDS-only barrier: orders the ds_writes without draining vmcnt (x prefetch
// stays in flight; compiler waits vmcnt at first use).
__device__ __forceinline__ void lds_barrier() {
    asm volatile("s_waitcnt lgkmcnt(0)\n\ts_barrier" ::: "memory");
}

__device__ __forceinline__ float tanh_fast(float u) {
    const float p = __builtin_amdgcn_exp2f(u * 2.8853900817779268f);
    return fmaf(-2.f, __builtin_amdgcn_rcpf(p + 1.f), 1.f);
}

__global__ __launch_bounds__(512, 2)
void rnn_persist(const float* __restrict__ x,
                 const float* __restrict__ W_ih,
                 const float* __restrict__ W_hh,
                 const float* __restrict__ b_ih,
                 const float* __restrict__ b_hh,
                 const float* __restrict__ W_out,
                 const float* __restrict__ b_out,
                 float* __restrict__ out)
{
    __shared__ __align__(16) half_t hbuf[2][16 * HSTRH];   // 2 x 768 B

    const int tid = threadIdx.x;
    const int b   = blockIdx.x;
    const int w   = tid >> 6;         // waves 0-3: MFMA rows 0-127; 4-7: vector rows 128-255
    const int l   = tid & 63;
    const bool is_mfma = (w < 4);

    hbuf[0][hidx16(tid & 255)] = (half_t)0.f;   // h_0 = 0 (2-dup, same value)

    // ---------------- MFMA-path setup (waves 0-3) ----------------
    const int ln = l & 15;            // C/D col = lane&15
    const int kg = l >> 4;            // k-group 0..3
    // Padded-layout broadcast read offset (halfs): 24*(kg>>1) + 8*(kg&1).
    const int aoff = 24 * (kg >> 1) + 8 * (kg & 1);

    h8v wf[2][8];
    float wihv[2], cbv[2];
    // ---------------- vector-path setup (waves 4-7) ----------------
    const int tid2 = tid & 255;
    const int c    = tid2 & 15;       // K-chunk / DPP lane
    const int g2   = tid2 >> 4;       // row group 0..15 -> rows 128+8g2..+7
    h2 w2h[8][8];
    float wihS = 0.f, cbS = 0.f;
    int  widxS = 0;

    if (is_mfma) {
        #pragma unroll
        for (int rb = 0; rb < 2; ++rb) {
            #pragma unroll
            for (int kb = 0; kb < 8; ++kb) {
                const float* p = W_hh + (size_t)(32 * w + 16 * rb + ln) * HH
                                       + 32 * kb + 8 * kg;
                const float4 qa = *(const float4*)p;
                const float4 qb = *(const float4*)(p + 4);
                wf[rb][kb] = (h8v){(half_t)qa.x, (half_t)qa.y, (half_t)qa.z,
                                   (half_t)qa.w, (half_t)qb.x, (half_t)qb.y,
                                   (half_t)qb.z, (half_t)qb.w};
            }
        }
        #pragma unroll
        for (int rb = 0; rb < 2; ++rb) {
            const int o = 32 * w + 16 * rb + ln;
            wihv[rb] = W_ih[o];
            cbv[rb]  = b_ih[o] + b_hh[o];
        }
    } else {
        const int m[8] = {0, 2, 7, 5, 8, 10, 15, 13};
        #pragma unroll
        for (int s = 0; s < 8; ++s) {
            const int row_idx = 128 + 8 * g2 + ((c ^ m[s]) >> 1);
            const float* row = W_hh + (size_t)row_idx * HH + 16 * c;
            #pragma unroll
            for (int j = 0; j < 8; ++j)
                w2h[s][j] = (h2){(half_t)row[2 * j], (half_t)row[2 * j + 1]};
        }
        const int o = 128 + 8 * g2 + (c >> 1);
        wihS  = W_ih[o];
        cbS   = b_ih[o] + b_hh[o];
        widxS = hidx16(o);
    }
    const bool writer = (l < 16);

    __syncthreads();

    const float* xb = x + b * TT;
    const f4v zf = {0.f, 0.f, 0.f, 0.f};

    auto step = [&](const half_t* __restrict__ cur, half_t* __restrict__ nxt,
                    float xt) __attribute__((always_inline)) {
        if (is_mfma) {
            // Broadcast A reads from the padded layout: af[kb] at
            // cur + aoff + 48*kb halfs (16-lane same-addr groups).
            const half_t* ap = cur + aoff;
            h8v af[8];
            #pragma unroll
            for (int kb = 0; kb < 8; ++kb)
                af[kb] = *(const h8v*)(ap + 48 * kb);

            const float u0p = fmaf(xt, wihv[0], cbv[0]);
            const float u1p = fmaf(xt, wihv[1], cbv[1]);

            __builtin_amdgcn_s_setprio(1);
            f4v a00 = mfma16(af[0], wf[0][0], zf);
            f4v a01 = mfma16(af[4], wf[0][4], zf);
            a00 = mfma16(af[1], wf[0][1], a00);
            a01 = mfma16(af[5], wf[0][5], a01);
            a00 = mfma16(af[2], wf[0][2], a00);
            a01 = mfma16(af[6], wf[0][6], a01);
            a00 = mfma16(af[3], wf[0][3], a00);
            a01 = mfma16(af[7], wf[0][7], a01);
            f4v a10 = mfma16(af[0], wf[1][0], zf);
            f4v a11 = mfma16(af[4], wf[1][4], zf);
            a10 = mfma16(af[1], wf[1][1], a10);
            a11 = mfma16(af[5], wf[1][5], a11);
            a10 = mfma16(af[2], wf[1][2], a10);
            a11 = mfma16(af[6], wf[1][6], a11);
            a10 = mfma16(af[3], wf[1][3], a10);
            a11 = mfma16(af[7], wf[1][7], a11);
            __builtin_amdgcn_s_setprio(0);

            if (writer) {
                const float t0 = tanh_fast(u0p + (a00.x + a01.x));
                nxt[hidx16(32 * w + ln)] = (half_t)t0;        // rb0 early
                const float t1 = tanh_fast(u1p + (a10.x + a11.x));
                nxt[hidx16(32 * w + 16 + ln)] = (half_t)t1;   // rb1
            }
        } else {
            // Vector path: chunk c, 2x hoct (j-outer, dot2 starts lgkmcnt(1)).
            const hoct* hq = (const hoct*)(cur + c * HSTRH);
            const hoct qa = hq[0], qb = hq[1];

            float acc[8];
            #pragma unroll
            for (int s = 0; s < 8; ++s) acc[s] = fdot2f(w2h[s][0], qa.v[0], 0.f);
            #pragma unroll
            for (int s = 0; s < 8; ++s) acc[s] = fdot2f(w2h[s][1], qa.v[1], acc[s]);
            #pragma unroll
            for (int s = 0; s < 8; ++s) acc[s] = fdot2f(w2h[s][2], qa.v[2], acc[s]);
            #pragma unroll
            for (int s = 0; s < 8; ++s) acc[s] = fdot2f(w2h[s][3], qa.v[3], acc[s]);
            #pragma unroll
            for (int s = 0; s < 8; ++s) acc[s] = fdot2f(w2h[s][4], qb.v[0], acc[s]);
            #pragma unroll
            for (int s = 0; s < 8; ++s) acc[s] = fdot2f(w2h[s][5], qb.v[1], acc[s]);
            #pragma unroll
            for (int s = 0; s < 8; ++s) acc[s] = fdot2f(w2h[s][6], qb.v[2], acc[s]);
            #pragma unroll
            for (int s = 0; s < 8; ++s) acc[s] = fdot2f(w2h[s][7], qb.v[3], acc[s]);

            float b0 = dppadd<0x128>(acc[0], acc[4]);   // xor8
            float b1 = dppadd<0x128>(acc[1], acc[5]);
            float b2 = dppadd<0x128>(acc[2], acc[6]);
            float b3 = dppadd<0x128>(acc[3], acc[7]);
            float c0 = dppadd<0x141>(b0, b2);           // xor7
            float c1 = dppadd<0x141>(b1, b3);
            float d  = dppadd<0x4E>(c0, c1);            // xor2
            float e  = dppadd<0xB1>(d, d);              // xor1

            const float th = tanh_fast(fmaf(xt, wihS, cbS) + e);
            nxt[widxS] = (half_t)th;   // 2-dup same-addr, same value
        }
        lds_barrier();   // lgkm-only: x prefetch stays in flight
    };

    // x block-prefetch: block's two float4s fetched one 8-step block ahead.
    float4 xa = *(const float4*)(xb + 0);
    float4 xc = *(const float4*)(xb + 4);
    for (int t = 0; t < TT; t += 8) {
        const int tn = (t + 8 < TT) ? (t + 8) : t;   // clamped (last block refetch)
        const float4 xa_n = *(const float4*)(xb + tn);
        const float4 xc_n = *(const float4*)(xb + tn + 4);
        step(hbuf[0], hbuf[1], xa.x);
        step(hbuf[1], hbuf[0], xa.y);
        step(hbuf[0], hbuf[1], xa.z);
        step(hbuf[1], hbuf[0], xa.w);
        step(hbuf[0], hbuf[1], xc.x);
        step(hbuf[1], hbuf[0], xc.y);
        step(hbuf[0], hbuf[1], xc.z);
        step(hbuf[1], hbuf[0], xc.w);
        xa = xa_n;
        xc = xc_n;
    }

    // Head: h_T in hbuf[0] (TT % 8 == 0). out[b,p] = b_out[p] + W_out[p,:].h_T
    if (tid < PP) {
        const float* wo = W_out + tid * HH;
        float s0 = 0.f, s1 = 0.f, s2 = 0.f, s3 = 0.f;
        #pragma unroll
        for (int h = 0; h < HH; h += 4) {
            s0 = fmaf(wo[h + 0], (float)hbuf[0][hidx16(h + 0)], s0);
            s1 = fmaf(wo[h + 1], (float)hbuf[0][hidx16(h + 1)], s1);
            s2 = fmaf(wo[h + 2], (float)hbuf[0][hidx16(h + 2)], s2);
            s3 = fmaf(wo[h + 3], (float)hbuf[0][hidx16(h + 3)], s3);
        }
        out[b * PP + tid] = b_out[tid] + (s0 + s1) + (s2 + s3);
    }
}

extern "C" void kernel_launch(void* const* d_in, const int* in_sizes, int n_in,
                              void* d_out, int out_size, void* d_ws, size_t ws_size,
                              hipStream_t stream) {
    const float* x     = (const float*)d_in[0];
    const float* W_ih  = (const float*)d_in[1];
    const float* W_hh  = (const float*)d_in[2];
    const float* b_ih  = (const float*)d_in[3];
    const float* b_hh  = (const float*)d_in[4];
    const float* W_out = (const float*)d_in[5];
    const float* b_out = (const float*)d_in[6];
    float* out = (float*)d_out;

    rnn_persist<<<BB, 512, 0, stream>>>(x, W_ih, W_hh, b_ih, b_hh, W_out, b_out, out);
}

// Round 22
// 865.504 us; speedup vs baseline: 1.2175x; 1.2175x over previous
//
#include <hip/hip_runtime.h>

// RNN: h_t = tanh(x[b,t]*W_ih + b_ih + b_hh + h_{t-1} @ W_hh^T), out = h_T @ W_out^T + b_out
// B=256 T=2048 H=256 P=24, fp32 in/out. One WG/batch (256 WGs = 256 CUs), 512 thr, 8 waves.
//
// Round-28: FULLY INDEPENDENT MFMAs (split-K=8). R21's hybrid regressed
// (1054us, step 1240cyc with LESS issue load than R17's 990) -> the step is
// serial-latency-bound per wave, not issue-bound; latency hiding needs
// same-structure partner waves. And R17's MfmaUtil arithmetic (535 cyc
// "busy" for 32 MFMA/SIMD whose throughput cost is 155) shows the MFMA
// pipe time is dominated by DEPENDENCY-CHAIN latency (4 chains of depth 4).
// Fix: all 16 MFMAs per wave are independent (zero-C operand, acc arrays
// p0[8]/p1[8], static indices); K-reduce moves to a 7-add .x tree on
// writer lanes (rows replicated -> only .x matters). Serial chain becomes
// DS-latency + ONE MFMA latency + tree + tanh + write + barrier.
// Cost: +48 VGPR acc (~180 total < 256 cap at 2 waves/EU; spill would show
// as FETCH_SIZE explosion) and 14 writer-lane adds (hide under other rb).
// Null result (+-3%) => exposure is the DS/barrier serial chain => R17 is
// the practical plateau.
// A/B layout (R14-R17-verified): A = h broadcast, lane l reads
// h[32kb+8*(l>>4)+j] (one ds_read_b128/kb, 16-lane same-addr groups,
// conflict-free); B = W rows in regs, same k-formula -> HW k-permutation
// cancels; C/D col = lane&15. FP reassociation -> absmax few-e-3 class.
// Locked-in: fp16 h storage; lgkm-only barrier; setprio around MFMA
// cluster; early rb0 tail; hoisted u_pre; x block-prefetch; fp32 tanh
// (exp2/rcp); fp32 head on tid<24; launch_bounds(512,2).

#define BB 256
#define TT 2048
#define HH 256
#define PP 24

typedef _Float16 half_t;
typedef _Float16 h8v __attribute__((ext_vector_type(8)));
typedef float    f4v __attribute__((ext_vector_type(4)));

__device__ __forceinline__ f4v mfma16(h8v a, h8v b, f4v c) {
    return __builtin_amdgcn_mfma_f32_16x16x32_f16(a, b, c, 0, 0, 0);
}

// LDS-only barrier: orders the ds_writes without draining vmcnt (x prefetch
// stays in flight; compiler waits vmcnt at first use).
__device__ __forceinline__ void lds_barrier() {
    asm volatile("s_waitcnt lgkmcnt(0)\n\ts_barrier" ::: "memory");
}

__device__ __forceinline__ float tanh_fast(float u) {
    const float p = __builtin_amdgcn_exp2f(u * 2.8853900817779268f);
    return fmaf(-2.f, __builtin_amdgcn_rcpf(p + 1.f), 1.f);
}

__global__ __launch_bounds__(512, 2)
void rnn_persist(const float* __restrict__ x,
                 const float* __restrict__ W_ih,
                 const float* __restrict__ W_hh,
                 const float* __restrict__ b_ih,
                 const float* __restrict__ b_hh,
                 const float* __restrict__ W_out,
                 const float* __restrict__ b_out,
                 float* __restrict__ out)
{
    __shared__ __align__(16) half_t hbuf[2][HH];   // 2 x 512 B

    const int tid  = threadIdx.x;
    const int b    = blockIdx.x;
    const int w    = tid >> 6;        // wave 0..7 -> owns y[32w .. 32w+31]
    const int l    = tid & 63;
    const int ln   = l & 15;          // col within 16-block (C/D col = lane&15)
    const int kg   = l >> 4;          // k-group 0..3 (8 k-slots each)

    hbuf[0][tid & 255] = (half_t)0.f; // h_0 = 0 (2-dup same-addr, same value)

    // B-operand weights in regs: wf[rb][kb] = W[32w+16rb+ln][32kb+8kg+j],
    // j=0..7 (f16). 2*8*4 = 64 VGPRs.
    h8v wf[2][8];
    #pragma unroll
    for (int rb = 0; rb < 2; ++rb) {
        #pragma unroll
        for (int kb = 0; kb < 8; ++kb) {
            const float* p = W_hh + (size_t)(32 * w + 16 * rb + ln) * HH
                                   + 32 * kb + 8 * kg;
            const float4 qa = *(const float4*)p;
            const float4 qb = *(const float4*)(p + 4);
            wf[rb][kb] = (h8v){(half_t)qa.x, (half_t)qa.y, (half_t)qa.z,
                               (half_t)qa.w, (half_t)qb.x, (half_t)qb.y,
                               (half_t)qb.z, (half_t)qb.w};
        }
    }

    // Rows this lane finalizes (lanes 0-15 only): 32w + 16rb + ln.
    float wihv[2], cbv[2];
    #pragma unroll
    for (int rb = 0; rb < 2; ++rb) {
        const int o = 32 * w + 16 * rb + ln;
        wihv[rb] = W_ih[o];
        cbv[rb]  = b_ih[o] + b_hh[o];
    }
    const bool writer = (l < 16);

    __syncthreads();

    const float* xb = x + b * TT;
    const f4v zf = {0.f, 0.f, 0.f, 0.f};   // shared zero C operand

    auto step = [&](const half_t* __restrict__ cur, half_t* __restrict__ nxt,
                    float xt) __attribute__((always_inline)) {
        // A fragments: 8 broadcast ds_read_b128 (base + kg*16 + kb*64 bytes).
        const h8v* hp = (const h8v*)(cur + 8 * kg);
        h8v af[8];
        #pragma unroll
        for (int kb = 0; kb < 8; ++kb) af[kb] = hp[4 * kb];

        // Hoisted input projection (independent of the matvec).
        const float u0p = fmaf(xt, wihv[0], cbv[0]);
        const float u1p = fmaf(xt, wihv[1], cbv[1]);

        // 16 INDEPENDENT MFMAs (zero-C): no dep chains on the matrix pipe.
        // rb0's 8 issue first so its tail overlaps rb1's matrix work.
        f4v p0[8], p1[8];
        __builtin_amdgcn_s_setprio(1);
        #pragma unroll
        for (int kb = 0; kb < 8; ++kb) p0[kb] = mfma16(af[kb], wf[0][kb], zf);
        #pragma unroll
        for (int kb = 0; kb < 8; ++kb) p1[kb] = mfma16(af[kb], wf[1][kb], zf);
        __builtin_amdgcn_s_setprio(0);

        // Tails (writer lanes): 7-add .x tree per rb (rows replicated).
        if (writer) {
            const float y0 = ((p0[0].x + p0[1].x) + (p0[2].x + p0[3].x))
                           + ((p0[4].x + p0[5].x) + (p0[6].x + p0[7].x));
            nxt[32 * w + ln] = (half_t)tanh_fast(u0p + y0);        // rb0 early
            const float y1 = ((p1[0].x + p1[1].x) + (p1[2].x + p1[3].x))
                           + ((p1[4].x + p1[5].x) + (p1[6].x + p1[7].x));
            nxt[32 * w + 16 + ln] = (half_t)tanh_fast(u1p + y1);   // rb1
        }
        lds_barrier();   // lgkm-only: x prefetch stays in flight
    };

    // x block-prefetch: block's two float4s fetched one 8-step block ahead.
    float4 xa = *(const float4*)(xb + 0);
    float4 xc = *(const float4*)(xb + 4);
    for (int t = 0; t < TT; t += 8) {
        const int tn = (t + 8 < TT) ? (t + 8) : t;   // clamped (last block refetch)
        const float4 xa_n = *(const float4*)(xb + tn);
        const float4 xc_n = *(const float4*)(xb + tn + 4);
        step(hbuf[0], hbuf[1], xa.x);
        step(hbuf[1], hbuf[0], xa.y);
        step(hbuf[0], hbuf[1], xa.z);
        step(hbuf[1], hbuf[0], xa.w);
        step(hbuf[0], hbuf[1], xc.x);
        step(hbuf[1], hbuf[0], xc.y);
        step(hbuf[0], hbuf[1], xc.z);
        step(hbuf[1], hbuf[0], xc.w);
        xa = xa_n;
        xc = xc_n;
    }

    // Head: h_T in hbuf[0] (TT % 8 == 0). out[b,p] = b_out[p] + W_out[p,:].h_T
    if (tid < PP) {
        const float* wo = W_out + tid * HH;
        float s0 = 0.f, s1 = 0.f, s2 = 0.f, s3 = 0.f;
        #pragma unroll
        for (int h = 0; h < HH; h += 4) {
            s0 = fmaf(wo[h + 0], (float)hbuf[0][h + 0], s0);
            s1 = fmaf(wo[h + 1], (float)hbuf[0][h + 1], s1);
            s2 = fmaf(wo[h + 2], (float)hbuf[0][h + 2], s2);
            s3 = fmaf(wo[h + 3], (float)hbuf[0][h + 3], s3);
        }
        out[b * PP + tid] = b_out[tid] + (s0 + s1) + (s2 + s3);
    }
}

extern "C" void kernel_launch(void* const* d_in, const int* in_sizes, int n_in,
                              void* d_out, int out_size, void* d_ws, size_t ws_size,
                              hipStream_t stream) {
    const float* x     = (const float*)d_in[0];
    const float* W_ih  = (const float*)d_in[1];
    const float* W_hh  = (const float*)d_in[2];
    const float* b_ih  = (const float*)d_in[3];
    const float* b_hh  = (const float*)d_in[4];
    const float* W_out = (const float*)d_in[5];
    const float* b_out = (const float*)d_in[6];
    float* out = (float*)d_out;

    rnn_persist<<<BB, 512, 0, stream>>>(x, W_ih, W_hh, b_ih, b_hh, W_out, b_out, out);
}